// Round 4
// baseline (1756.333 us; speedup 1.0000x reference)
//
#include <hip/hip_runtime.h>

// Batched time-varying LQR: Riccati backward pass + forward rollout.
// T=64, B=128, NS=64 (state), NC=32 (control), NSC=96.
// One workgroup (512 threads = 8 waves) per batch element.
//
// R4:
//  - (4,4) register-tiled GEMMs; V fragments read row-contiguous via symmetry
//    (V[s0..3][u] = Vs[u][s0..3]) -> 2 x b128 per 16 FMAs (was 3.25 per 12).
//    Block LDS instruction count cut ~55% (R3 was LDS-pipe-bound).
//  - Rank-1 triangular solves: forward solve chain 2112->~300 cy; deferred
//    backsolve parity-split 2 lanes/column (waves 2-4, shfl_xor exchange).
//  - q = c + F^T h moved to Qu-phase wave 7 (idle there); phase D = chol only.
//  - Barriers 6->5 backward (F's barrier folded into next W#1), 3->2 forward.
//  - Kept from R2/R3: async global_load_lds + counted vmcnt, Y-form Riccati,
//    register wave-parallel Cholesky, deferred backsolve.

constexpr int T_   = 64;
constexpr int B_   = 128;
constexpr int NS_  = 64;
constexpr int NC_  = 32;
constexpr int NSC_ = 96;

// ---- LDS layout (floats). Total 37160 floats = 148,640 B. ----
constexpr int OFF_VS   = 0;       // Vs [64][68]   (V, symmetric, stride 68)
constexpr int OFF_WS   = 4352;    // Ws [64][100]  (W = V F)  | fwd: Sfb[2][2304]
constexpr int OFF_QU   = 10752;   // Qu [32][100]  (Q rows 64..95 = [Qux|Quu])
constexpr int OFF_SS   = 13952;   // Ss [2][32][68] (Y buffers, double-buffered)
constexpr int OFF_LT   = 18304;   // LT [2][32][33] (chol factor^T, dbuf)
constexpr int OFF_INVD = 20416;   // invd[2][32]
constexpr int OFF_QV   = 20480;   // qv[96]+pad    | fwd: tau[96]
constexpr int OFF_HV   = 20580;   // hv[64]
constexpr int OFF_VV   = 20644;   // vv[64]+pad
constexpr int OFF_FB   = 20776;   // Fbuf[2][6144] (F linear [64][96])
constexpr int OFF_CU   = 33064;   // Cu [3072]     (C rows 64..95, linear [32][96])
constexpr int OFF_CF   = 36136;   // cfb[2][512]   (c @ +0..95, f @ +256..319)
constexpr int SMEM_F   = 37160;

typedef __attribute__((address_space(3))) void*       lds_vp;
typedef const __attribute__((address_space(1))) void* gas_vp;

__device__ __forceinline__ void g2l16(const float* g, float* l) {
  __builtin_amdgcn_global_load_lds((gas_vp)g, (lds_vp)l, 16, 0, 0);
}

__device__ __forceinline__ float rdlane(float v, int l) {
  return __builtin_bit_cast(float, __builtin_amdgcn_readlane(__builtin_bit_cast(int, v), l));
}

#define ASM_WAIT(S) asm volatile("s_waitcnt " S ::: "memory")
#define BAR()       __builtin_amdgcn_s_barrier()

__global__ __launch_bounds__(512) void lqr_all(
    const float* __restrict__ Cg, const float* __restrict__ cvg,
    const float* __restrict__ Fg, const float* __restrict__ fvg,
    const float* __restrict__ x0g, float* __restrict__ outg,
    float* __restrict__ Sws)
{
  const int b    = blockIdx.x;
  const int tid  = threadIdx.x;
  const int wid  = tid >> 6;
  const int lane = tid & 63;

  __shared__ float smem[SMEM_F];
  float (*Vs)[68]  = (float(*)[68]) (smem + OFF_VS);
  float (*Ws)[100] = (float(*)[100])(smem + OFF_WS);
  float (*Qu)[100] = (float(*)[100])(smem + OFF_QU);
  float* qv = smem + OFF_QV;
  float* hv = smem + OFF_HV;
  float* vv = smem + OFF_VV;

  for (int e = tid; e < 4352; e += 512) smem[e] = 0.f;
  if (tid < 64) vv[tid] = 0.f;

  // ---- hoisted per-thread tile indices ----
  const int b_r4 = (tid & 15) * 4;            // phase B (tid<384): W rows
  const int b_c4 = (tid >> 4) * 4;            // phase B: W cols (0..92)
  const int q_i0 = (tid / 24) * 4;            // phase Qu (tid<192)
  const int q_j0 = (tid % 24) * 4;
  const int tvs  = tid - 192;                 // VsD (192<=tid<448)
  const int v_r  = (tvs & 15) * 4;
  const int v_c  = ((tvs >> 4) & 15) * 4;
  const int tf2  = tid - 256;                 // phase F YtY (tid>=256)
  const int f_i  = ((tf2 >> 4) & 15) * 4;
  const int f_j  = (tf2 & 15) * 4;

  // deferred back-solve, parity-split: 2 lanes per column (tid 128..257)
  auto backsolve2 = [&](int pb, size_t tbn) {
    const int c = (tid - 128) >> 1;           // 0..64
    const int h = (tid - 128) & 1;            // row parity owned
    const float (*Sp)[68]  = (const float(*)[68])(smem + OFF_SS + pb * 2176);
    const float (*LTp)[33] = (const float(*)[33])(smem + OFF_LT + pb * 1056);
    const float* ivp = smem + OFF_INVD + pb * 32;
    float r[16];
#pragma unroll
    for (int m = 0; m < 16; ++m) r[m] = Sp[2 * m + h][c];
    float* Sg = Sws + tbn * 2080;
#pragma unroll
    for (int k = 31; k >= 0; --k) {
      const float cand  = r[k >> 1] * ivp[k];
      const float other = __shfl_xor(cand, 1);
      const float xk = ((k & 1) == h) ? cand : other;
      if ((k & 1) == h) Sg[k * 65 + c] = xk;
#pragma unroll
      for (int m = 0; m <= (k - 1) >> 1; ++m) {
        if (h < k - 2 * m)                    // compile-time true except last m
          r[m] -= LTp[2 * m + h][k] * xk;     // L[k][i] = LTp[i][k]
      }
    }
  };

  // ---- prologue staging: F_63 (3/wave), c/f_63 (wave 7) ----
  {
    const size_t tb0 = (size_t)(T_ - 1) * B_ + b;
    if (wid == 7) {
      const int o = lane * 4;
      g2l16(cvg + tb0 * 96 + (o < 96 ? o : 92), smem + OFF_CF);
      g2l16(fvg + tb0 * 64 + (o < 64 ? o : 60), smem + OFF_CF + 256);
    }
    const float* Fbase = Fg + tb0 * (NS_ * NSC_);
#pragma unroll
    for (int r = 0; r < 3; ++r) {
      const int q = wid * 3 + r;
      g2l16(Fbase + q * 256 + lane * 4, smem + OFF_FB + q * 256);
    }
  }

  int cur = 0;

  // ================= backward Riccati pass =================
  for (int t = T_ - 1; t >= 0; --t) {
    const size_t tb = (size_t)t * B_ + b;
    float4 cxa0 = {}, cxa1 = {}, cxb0 = {}, cxb1 = {};

    // ---- TOP staging (per-wave vmem issue order is load-bearing):
    //  waves 0-2: 4 Cu + 3 F ; waves 3-6: 4 Cxx reg + 3 F ; wave 7: 2 cf + 3 F
    {
      if (wid < 3) {
        const float* CuB = Cg + tb * 9216 + 64 * 96;
#pragma unroll
        for (int r = 0; r < 4; ++r) {
          const int q = wid * 4 + r;          // 0..11
          g2l16(CuB + q * 256 + lane * 4, smem + OFF_CU + q * 256);
        }
      } else if (wid < 7) {
        const float* Cb = Cg + tb * 9216;
        cxa0 = *(const float4*)(Cb + (v_r + 0) * 96 + v_c);
        cxa1 = *(const float4*)(Cb + (v_r + 1) * 96 + v_c);
        cxb0 = *(const float4*)(Cb + (v_r + 2) * 96 + v_c);
        cxb1 = *(const float4*)(Cb + (v_r + 3) * 96 + v_c);
      }
      const int tp = (t > 0) ? (t - 1) : 0;   // clamp keeps counts uniform
      const size_t tbp = (size_t)tp * B_ + b;
      if (wid == 7) {
        float* cdst = smem + OFF_CF + (cur ^ 1) * 512;
        const int o = lane * 4;
        g2l16(cvg + tbp * 96 + (o < 96 ? o : 92), cdst);
        g2l16(fvg + tbp * 64 + (o < 64 ? o : 60), cdst + 256);
      }
      const float* Fbase = Fg + tbp * (NS_ * NSC_);
      float* fdst = smem + OFF_FB + (cur ^ 1) * 6144;
#pragma unroll
      for (int r = 0; r < 3; ++r) {
        const int q = wid * 3 + r;
        g2l16(Fbase + q * 256 + lane * 4, fdst + q * 256);
      }
    }

    // W#1: drain prev-iter F/cf; keep this iter's issues in flight
    if (wid == 7) { ASM_WAIT("vmcnt(5) lgkmcnt(0)"); }
    else         { ASM_WAIT("vmcnt(7) lgkmcnt(0)"); }
    BAR();

    const float* Fb = smem + OFF_FB + cur * 6144;
    const float* cf = smem + OFF_CF + cur * 512;

    // ---- phase B: W = V F (384 thr, 4x4 tiles, V-symmetric row reads)
    //              h = v + V f (tid 384..447)
    if (tid < 384) {
      float acc[4][4];
#pragma unroll
      for (int a2 = 0; a2 < 4; ++a2)
#pragma unroll
        for (int j = 0; j < 4; ++j) acc[a2][j] = 0.f;
#pragma unroll 4
      for (int u = 0; u < 64; ++u) {
        const float4 va = *(const float4*)&Vs[u][b_r4];   // V[b_r4..+3][u] (sym)
        const float4 fb = *(const float4*)(Fb + u * 96 + b_c4);
        const float av[4] = {va.x, va.y, va.z, va.w};
        const float bv[4] = {fb.x, fb.y, fb.z, fb.w};
#pragma unroll
        for (int a2 = 0; a2 < 4; ++a2)
#pragma unroll
          for (int j = 0; j < 4; ++j) acc[a2][j] += av[a2] * bv[j];
      }
#pragma unroll
      for (int a2 = 0; a2 < 4; ++a2)
        *(float4*)&Ws[b_r4 + a2][b_c4] =
            make_float4(acc[a2][0], acc[a2][1], acc[a2][2], acc[a2][3]);
    } else if (tid < 448) {
      const int s = tid - 384;
      float acc = vv[s];
#pragma unroll
      for (int u4 = 0; u4 < 16; ++u4) {
        const float4 vr = *(const float4*)&Vs[s][u4 * 4];
        const float4 fr = *(const float4*)(cf + 256 + u4 * 4);
        acc += vr.x * fr.x + vr.y * fr.y + vr.z * fr.z + vr.w * fr.w;
      }
      hv[s] = acc;
    }

    // W#2: Cu staging (+Cxx regs) complete; keep 3 F (+cf kept implicitly fine)
    ASM_WAIT("vmcnt(3) lgkmcnt(0)");
    BAR();

    // ---- phase Qu/VsD/q (all 8 waves):
    //  tid<192: Qu = Cu + Fu^T W (4x4) | tid<448: Vs = Cxx + Fx^T W (4x4)
    //  wave 7: q = c + F^T h
    if (tid < 192) {
      float a[4][4];
#pragma unroll
      for (int a2 = 0; a2 < 4; ++a2) {
        const float4 cu = *(const float4*)(smem + OFF_CU + (q_i0 + a2) * 96 + q_j0);
        a[a2][0] = cu.x; a[a2][1] = cu.y; a[a2][2] = cu.z; a[a2][3] = cu.w;
      }
#pragma unroll 4
      for (int u = 0; u < 64; ++u) {
        const float4 fu = *(const float4*)(Fb + u * 96 + 64 + q_i0);
        const float4 w4 = *(const float4*)&Ws[u][q_j0];
        const float av[4] = {fu.x, fu.y, fu.z, fu.w};
        const float wv[4] = {w4.x, w4.y, w4.z, w4.w};
#pragma unroll
        for (int a2 = 0; a2 < 4; ++a2)
#pragma unroll
          for (int j = 0; j < 4; ++j) a[a2][j] += av[a2] * wv[j];
      }
#pragma unroll
      for (int a2 = 0; a2 < 4; ++a2)
        *(float4*)&Qu[q_i0 + a2][q_j0] =
            make_float4(a[a2][0], a[a2][1], a[a2][2], a[a2][3]);
    } else if (tid < 448) {
      float a[4][4];
      a[0][0] = cxa0.x; a[0][1] = cxa0.y; a[0][2] = cxa0.z; a[0][3] = cxa0.w;
      a[1][0] = cxa1.x; a[1][1] = cxa1.y; a[1][2] = cxa1.z; a[1][3] = cxa1.w;
      a[2][0] = cxb0.x; a[2][1] = cxb0.y; a[2][2] = cxb0.z; a[2][3] = cxb0.w;
      a[3][0] = cxb1.x; a[3][1] = cxb1.y; a[3][2] = cxb1.z; a[3][3] = cxb1.w;
#pragma unroll 4
      for (int u = 0; u < 64; ++u) {
        const float4 fx = *(const float4*)(Fb + u * 96 + v_r);
        const float4 w4 = *(const float4*)&Ws[u][v_c];
        const float av[4] = {fx.x, fx.y, fx.z, fx.w};
        const float wv[4] = {w4.x, w4.y, w4.z, w4.w};
#pragma unroll
        for (int a2 = 0; a2 < 4; ++a2)
#pragma unroll
          for (int j = 0; j < 4; ++j) a[a2][j] += av[a2] * wv[j];
      }
#pragma unroll
      for (int a2 = 0; a2 < 4; ++a2)
        *(float4*)&Vs[v_r + a2][v_c] =
            make_float4(a[a2][0], a[a2][1], a[a2][2], a[a2][3]);
    } else {
      const int j = tid - 448;                // 0..63 ; row j and (j+64 if j<32)
      float acc0 = cf[j];
      float acc1 = (j < 32) ? cf[64 + j] : 0.f;
#pragma unroll 4
      for (int s2 = 0; s2 < 64; ++s2) {
        const float hs = hv[s2];
        acc0 += Fb[s2 * 96 + j] * hs;
        if (j < 32) acc1 += Fb[s2 * 96 + 64 + j] * hs;
      }
      qv[j] = acc0;
      if (j < 32) qv[64 + j] = acc1;
    }

    ASM_WAIT("lgkmcnt(0)");
    BAR();

    // ---- phase D: register Cholesky of Quu (lanes 0-31) -> LT[cur], invd[cur]
    if (tid < 32) {
      const int i = tid;
      float a[32];
#pragma unroll
      for (int k = 0; k < 32; ++k) a[k] = Qu[i][64 + k];
      float (*LTc)[33] = (float(*)[33])(smem + OFF_LT + cur * 1056);
      float* ivc = smem + OFF_INVD + cur * 32;
#pragma unroll
      for (int j = 0; j < 32; ++j) {
        const float d   = rdlane(a[j], j);
        const float rin = 1.0f / sqrtf(d);
        const float l   = a[j] * rin;         // L[i][j] (valid i>=j)
        LTc[j][i] = l;
        if (i == 0) ivc[j] = rin;
#pragma unroll
        for (int k = j + 1; k < 32; ++k) {
          const float lkj = rdlane(l, k);
          a[k] = fmaf(-l, lkj, a[k]);
        }
      }
    }

    ASM_WAIT("lgkmcnt(0)");
    BAR();

    // ---- phase E: forward solve Y = L^{-1}[Qux|qu] (tid<65, rank-1 form)
    //              || deferred back-solve of step t+1 (tid 128..257)
    if (tid < 65) {
      const float (*LTc)[33] = (const float(*)[33])(smem + OFF_LT + cur * 1056);
      const float* ivc = smem + OFF_INVD + cur * 32;
      float r[32];
#pragma unroll
      for (int i2 = 0; i2 < 32; ++i2)
        r[i2] = (tid < 64) ? Qu[i2][tid] : qv[64 + i2];
#pragma unroll
      for (int i2 = 0; i2 < 32; ++i2) {
        const float yi = r[i2] * ivc[i2];
        r[i2] = yi;
#pragma unroll
        for (int k = i2 + 1; k < 32; ++k) r[k] -= LTc[i2][k] * yi;
      }
      float (*Sc)[68] = (float(*)[68])(smem + OFF_SS + cur * 2176);
#pragma unroll
      for (int i2 = 0; i2 < 32; ++i2) Sc[i2][tid] = r[i2];
    } else if (tid >= 128 && tid < 258) {
      if (t != T_ - 1) backsolve2(cur ^ 1, (size_t)(t + 1) * B_ + b);
    }

    ASM_WAIT("lgkmcnt(0)");
    BAR();

    // ---- phase F: V -= Y^T Y (tid>=256, 4x4); vn = qx - Y^T y (tid<64)
    {
      const float (*Sc)[68] = (const float(*)[68])(smem + OFF_SS + cur * 2176);
      if (tid >= 256) {
        float p[4][4];
#pragma unroll
        for (int a2 = 0; a2 < 4; ++a2)
#pragma unroll
          for (int j = 0; j < 4; ++j) p[a2][j] = 0.f;
#pragma unroll 4
        for (int m = 0; m < 32; ++m) {
          const float4 ya = *(const float4*)&Sc[m][f_i];
          const float4 yb = *(const float4*)&Sc[m][f_j];
          const float av[4] = {ya.x, ya.y, ya.z, ya.w};
          const float bv[4] = {yb.x, yb.y, yb.z, yb.w};
#pragma unroll
          for (int a2 = 0; a2 < 4; ++a2)
#pragma unroll
            for (int j = 0; j < 4; ++j) p[a2][j] += av[a2] * bv[j];
        }
#pragma unroll
        for (int a2 = 0; a2 < 4; ++a2) {
          float4 v4 = *(const float4*)&Vs[f_i + a2][f_j];
          v4.x -= p[a2][0]; v4.y -= p[a2][1]; v4.z -= p[a2][2]; v4.w -= p[a2][3];
          *(float4*)&Vs[f_i + a2][f_j] = v4;
        }
      } else if (tid < 64) {
        float acc = qv[tid];
#pragma unroll 4
        for (int m = 0; m < 32; ++m) acc -= Sc[m][tid] * Sc[m][64];
        vv[tid] = acc;
      }
    }
    // no trailing barrier: next W#1 (wait+bar) covers all hazards
    cur ^= 1;
  }

  // ---- epilogue: back-solve for t=0 (its Y/LT/invd live in buffer 1)
  ASM_WAIT("vmcnt(0) lgkmcnt(0)");
  BAR();
  if (tid >= 128 && tid < 258) backsolve2(1, (size_t)b);
  ASM_WAIT("vmcnt(0) lgkmcnt(0)");   // S stores must land before fwd re-reads
  BAR();

  // ================= forward rollout =================
  float* tf = smem + OFF_QV;                   // tau: [0:64]=x, [64:96]=u
  if (tid < 64) tf[tid] = x0g[(size_t)b * 64 + tid];

  auto stage_fwd = [&](int ts, int nb) {       // 6 instrs/wave: S(2) F(3) f(1)
    const size_t tbs = (size_t)ts * B_ + b;
    const float* Sb = Sws + tbs * 2080;
    float* sdst = smem + OFF_WS + nb * 2304;
#pragma unroll
    for (int r = 0; r < 2; ++r) {
      int q = wid * 2 + r; if (q > 8) q = 8;   // 9 chunks, dup tail (benign)
      const int off = q * 256 + lane * 4;
      g2l16(Sb + (off < 2080 ? off : 2076), sdst + q * 256);
    }
    const float* Fbase = Fg + tbs * (NS_ * NSC_);
    float* fdst = smem + OFF_FB + nb * 6144;
#pragma unroll
    for (int r = 0; r < 3; ++r) {
      const int q = wid * 3 + r;
      g2l16(Fbase + q * 256 + lane * 4, fdst + q * 256);
    }
    const int o = lane * 4;
    g2l16(fvg + tbs * 64 + (o < 64 ? o : 60), smem + OFF_CF + nb * 512);
  };

  stage_fwd(0, 0);
  cur = 0;
  const int s4 = tid >> 2, l4 = tid & 3;       // x-row ownership (tid<256)
  for (int t = 0; t < T_; ++t) {
    const size_t tb = (size_t)t * B_ + b;
    stage_fwd((t < T_ - 1) ? t + 1 : T_ - 1, cur ^ 1);
    ASM_WAIT("vmcnt(6) lgkmcnt(0)");
    BAR();

    const float* Fbc = smem + OFF_FB + cur * 6144;
    float ax = 0.f;

    // phase 1: emit x | ax = Fx x (tid<256, 4/row) | u = -(S tau) (tid>=256)
    if (tid < 64) outg[tb * 96 + tid] = tf[tid];
    if (tid < 256) {
      const float* Fr = Fbc + s4 * 96 + l4 * 16;
#pragma unroll
      for (int q = 0; q < 4; ++q) {
        const float4 fq = *(const float4*)(Fr + q * 4);
        const float4 xq = *(const float4*)&tf[l4 * 16 + q * 4];
        ax += fq.x * xq.x + fq.y * xq.y + fq.z * xq.z + fq.w * xq.w;
      }
    } else {
      const int m = (tid - 256) >> 3, l8 = tid & 7;
      const float* Sr = smem + OFF_WS + cur * 2304 + m * 65;
      float p = (l8 == 0) ? Sr[64] : 0.f;
      const int i0 = l8 * 8;
#pragma unroll
      for (int ii = 0; ii < 8; ++ii) p += Sr[i0 + ii] * tf[i0 + ii];
      p += __shfl_xor(p, 1); p += __shfl_xor(p, 2); p += __shfl_xor(p, 4);
      if (l8 == 0) tf[64 + m] = -p;
    }
    ASM_WAIT("lgkmcnt(0)");
    BAR();

    // phase 2: x_next = ax + Fu u + f -> tf[0:64] | emit u (tid 256..287)
    if (tid < 256) {
      const float* Fu = Fbc + s4 * 96 + 64 + l4 * 8;
      const float4 g0 = *(const float4*)(Fu);
      const float4 g1 = *(const float4*)(Fu + 4);
      const float4 u0 = *(const float4*)&tf[64 + l4 * 8];
      const float4 u1 = *(const float4*)&tf[64 + l4 * 8 + 4];
      float p = ax + g0.x * u0.x + g0.y * u0.y + g0.z * u0.z + g0.w * u0.w
                   + g1.x * u1.x + g1.y * u1.y + g1.z * u1.z + g1.w * u1.w;
      p += __shfl_xor(p, 1); p += __shfl_xor(p, 2);
      if (l4 == 0) tf[s4] = p + *(smem + OFF_CF + cur * 512 + s4);
    } else if (tid < 288) {
      const int m = tid - 256;
      outg[tb * 96 + 64 + m] = tf[64 + m];
    }
    ASM_WAIT("lgkmcnt(0)");
    BAR();
    cur ^= 1;
  }
}

extern "C" void kernel_launch(void* const* d_in, const int* in_sizes, int n_in,
                              void* d_out, int out_size, void* d_ws, size_t ws_size,
                              hipStream_t stream) {
  const float* C  = (const float*)d_in[0];
  const float* c  = (const float*)d_in[1];
  const float* F  = (const float*)d_in[2];
  const float* f  = (const float*)d_in[3];
  const float* x0 = (const float*)d_in[4];
  float* out = (float*)d_out;
  float* S   = (float*)d_ws;   // needs T*B*32*65*4 = 68.2 MB

  lqr_all<<<dim3(B_), dim3(512), 0, stream>>>(C, c, F, f, x0, out, S);
}

// Round 5
// 1690.363 us; speedup vs baseline: 1.0390x; 1.0390x over previous
//
#include <hip/hip_runtime.h>

// Batched time-varying LQR: Riccati backward pass + forward rollout.
// T=64, B=128, NS=64 (state), NC=32 (control), NSC=96.
// One workgroup (512 threads = 8 waves) per batch element.
//
// R5:
//  - v_pk_fma_f32 (packed fp32, 2 MAC/instr) in all 4 big GEMMs via op_sel
//    broadcast of the B-operand -> 8 pk-FMA per 4x4-tile K-step (was 16 FMA).
//    gfx950's 157 TF fp32 peak is the packed rate; plain FMA is half.
//  - Cu (C rows 64..95) addend loaded to REGISTERS by Qu-phase owner threads
//    (no LDS staging, no W#2 vmcnt coupling).
//  - Deferred backsolve moved into the Cholesky window (phase D) - it has no
//    dependency on the current chol; phase E = forward solve only.
//  - s_setprio(1) around the serial register Cholesky.
//  - Kept: async global_load_lds + counted vmcnt, Y-form Riccati, register
//    wave-parallel chol, 5 backward barriers, 2-barrier forward rollout.

constexpr int T_   = 64;
constexpr int B_   = 128;
constexpr int NS_  = 64;
constexpr int NC_  = 32;
constexpr int NSC_ = 96;

// ---- LDS layout (floats). Total 34088 floats = 136,352 B. ----
constexpr int OFF_VS   = 0;       // Vs [64][68]   (V, symmetric, stride 68)
constexpr int OFF_WS   = 4352;    // Ws [64][100]  (W = V F)  | fwd: Sfb[2][2304]
constexpr int OFF_QU   = 10752;   // Qu [32][100]  (Q rows 64..95 = [Qux|Quu])
constexpr int OFF_SS   = 13952;   // Ss [2][32][68] (Y buffers, double-buffered)
constexpr int OFF_LT   = 18304;   // LT [2][32][33] (chol factor^T, dbuf)
constexpr int OFF_INVD = 20416;   // invd[2][32]
constexpr int OFF_QV   = 20480;   // qv[96]+pad    | fwd: tau[96]
constexpr int OFF_HV   = 20580;   // hv[64]
constexpr int OFF_VV   = 20644;   // vv[64]+pad (+xnb pad to 20776)
constexpr int OFF_FB   = 20776;   // Fbuf[2][6144] (F linear [64][96])
constexpr int OFF_CF   = 33064;   // cfb[2][512]   (c @ +0..95, f @ +256..319)
constexpr int SMEM_F   = 34088;

typedef __attribute__((ext_vector_type(2))) float f32x2;
typedef __attribute__((ext_vector_type(4))) float f32x4;

typedef __attribute__((address_space(3))) void*       lds_vp;
typedef const __attribute__((address_space(1))) void* gas_vp;

__device__ __forceinline__ void g2l16(const float* g, float* l) {
  __builtin_amdgcn_global_load_lds((gas_vp)g, (lds_vp)l, 16, 0, 0);
}

__device__ __forceinline__ float rdlane(float v, int l) {
  return __builtin_bit_cast(float, __builtin_amdgcn_readlane(__builtin_bit_cast(int, v), l));
}

// d.{lo,hi} += a.{lo,hi} * b.lo   (broadcast low dword of src1)
__device__ __forceinline__ void pk_lo(f32x2& d, f32x2 a, f32x2 b) {
  asm("v_pk_fma_f32 %0, %1, %2, %0 op_sel:[0,0,0] op_sel_hi:[1,0,1]"
      : "+v"(d) : "v"(a), "v"(b));
}
// d.{lo,hi} += a.{lo,hi} * b.hi   (broadcast high dword of src1)
__device__ __forceinline__ void pk_hi(f32x2& d, f32x2 a, f32x2 b) {
  asm("v_pk_fma_f32 %0, %1, %2, %0 op_sel:[0,1,0] op_sel_hi:[1,1,1]"
      : "+v"(d) : "v"(a), "v"(b));
}

__device__ __forceinline__ f32x4 ld4(const float* p) { return *(const f32x4*)p; }
__device__ __forceinline__ void st4(float* p, float x, float y, float z, float w) {
  f32x4 v = {x, y, z, w};
  *(f32x4*)p = v;
}

#define ASM_WAIT(S) asm volatile("s_waitcnt " S ::: "memory")
#define BAR()       __builtin_amdgcn_s_barrier()

__global__ __launch_bounds__(512) void lqr_all(
    const float* __restrict__ Cg, const float* __restrict__ cvg,
    const float* __restrict__ Fg, const float* __restrict__ fvg,
    const float* __restrict__ x0g, float* __restrict__ outg,
    float* __restrict__ Sws)
{
  const int b    = blockIdx.x;
  const int tid  = threadIdx.x;
  const int wid  = tid >> 6;
  const int lane = tid & 63;

  __shared__ float smem[SMEM_F];
  float (*Vs)[68]  = (float(*)[68]) (smem + OFF_VS);
  float (*Ws)[100] = (float(*)[100])(smem + OFF_WS);
  float (*Qu)[100] = (float(*)[100])(smem + OFF_QU);
  float* qv = smem + OFF_QV;
  float* hv = smem + OFF_HV;
  float* vv = smem + OFF_VV;

  for (int e = tid; e < 4352; e += 512) smem[e] = 0.f;
  if (tid < 64) vv[tid] = 0.f;

  // ---- hoisted per-thread tile indices ----
  const int b_r4 = (tid & 15) * 4;            // phase B (tid<384): W rows
  const int b_c4 = (tid >> 4) * 4;            // phase B: W cols (0..92)
  const int q_i0 = (tid / 24) * 4;            // phase Qu (tid<192)
  const int q_j0 = (tid % 24) * 4;
  const int tvs  = tid - 192;                 // VsD (192<=tid<448)
  const int v_r  = (tvs & 15) * 4;
  const int v_c  = ((tvs >> 4) & 15) * 4;
  const int tf2  = tid - 256;                 // phase F YtY (tid>=256)
  const int f_i  = ((tf2 >> 4) & 15) * 4;
  const int f_j  = (tf2 & 15) * 4;

  // deferred back-solve, parity-split: 2 lanes per column (tid 128..257)
  auto backsolve2 = [&](int pb, size_t tbn) {
    const int c = (tid - 128) >> 1;           // 0..64
    const int h = (tid - 128) & 1;            // row parity owned
    const float (*Sp)[68]  = (const float(*)[68])(smem + OFF_SS + pb * 2176);
    const float (*LTp)[33] = (const float(*)[33])(smem + OFF_LT + pb * 1056);
    const float* ivp = smem + OFF_INVD + pb * 32;
    float r[16];
#pragma unroll
    for (int m = 0; m < 16; ++m) r[m] = Sp[2 * m + h][c];
    float* Sg = Sws + tbn * 2080;
#pragma unroll
    for (int k = 31; k >= 0; --k) {
      const float cand  = r[k >> 1] * ivp[k];
      const float other = __shfl_xor(cand, 1);
      const float xk = ((k & 1) == h) ? cand : other;
      if ((k & 1) == h) Sg[k * 65 + c] = xk;
#pragma unroll
      for (int m = 0; m <= (k - 1) >> 1; ++m) {
        if (h < k - 2 * m)
          r[m] -= LTp[2 * m + h][k] * xk;     // L[k][i] = LTp[i][k]
      }
    }
  };

  // ---- prologue staging: F_63 (3/wave), c/f_63 (wave 7) ----
  {
    const size_t tb0 = (size_t)(T_ - 1) * B_ + b;
    if (wid == 7) {
      const int o = lane * 4;
      g2l16(cvg + tb0 * 96 + (o < 96 ? o : 92), smem + OFF_CF);
      g2l16(fvg + tb0 * 64 + (o < 64 ? o : 60), smem + OFF_CF + 256);
    }
    const float* Fbase = Fg + tb0 * (NS_ * NSC_);
#pragma unroll
    for (int r = 0; r < 3; ++r) {
      const int q = wid * 3 + r;
      g2l16(Fbase + q * 256 + lane * 4, smem + OFF_FB + q * 256);
    }
  }

  int cur = 0;

  // ================= backward Riccati pass =================
  for (int t = T_ - 1; t >= 0; --t) {
    const size_t tb = (size_t)t * B_ + b;

    // C-tile addend registers: waves 0-2 -> Cu rows (Qu tiles),
    // waves 3-6 -> Cxx rows (VsD tiles), wave 7 -> none.
    f32x4 c0 = {0, 0, 0, 0}, c1 = {0, 0, 0, 0}, c2 = {0, 0, 0, 0}, c3 = {0, 0, 0, 0};

    // ---- TOP staging: each wave 0-6 issues 4 C reg loads + 3 F g2l16 (=7);
    //      wave 7 issues 2 cf g2l16 + 3 F g2l16 (=5).
    {
      const float* Cb = Cg + tb * 9216;
      if (wid < 3) {
        const float* cp = Cb + (64 + q_i0) * 96 + q_j0;
        c0 = ld4(cp); c1 = ld4(cp + 96); c2 = ld4(cp + 192); c3 = ld4(cp + 288);
      } else if (wid < 7) {
        const float* cp = Cb + v_r * 96 + v_c;
        c0 = ld4(cp); c1 = ld4(cp + 96); c2 = ld4(cp + 192); c3 = ld4(cp + 288);
      }
      const int tp = (t > 0) ? (t - 1) : 0;   // clamp keeps counts uniform
      const size_t tbp = (size_t)tp * B_ + b;
      if (wid == 7) {
        float* cdst = smem + OFF_CF + (cur ^ 1) * 512;
        const int o = lane * 4;
        g2l16(cvg + tbp * 96 + (o < 96 ? o : 92), cdst);
        g2l16(fvg + tbp * 64 + (o < 64 ? o : 60), cdst + 256);
      }
      const float* Fbase = Fg + tbp * (NS_ * NSC_);
      float* fdst = smem + OFF_FB + (cur ^ 1) * 6144;
#pragma unroll
      for (int r = 0; r < 3; ++r) {
        const int q = wid * 3 + r;
        g2l16(Fbase + q * 256 + lane * 4, fdst + q * 256);
      }
    }

    // W#1: drain prev-iter F/cf; keep this iter's issues in flight
    if (wid == 7) { ASM_WAIT("vmcnt(5) lgkmcnt(0)"); }
    else         { ASM_WAIT("vmcnt(7) lgkmcnt(0)"); }
    BAR();

    const float* Fb = smem + OFF_FB + cur * 6144;
    const float* cf = smem + OFF_CF + cur * 512;

    // ---- phase B: W = V F (384 thr, 4x4 tiles, packed FMA)
    //              h = v + V f (tid 384..447)
    if (tid < 384) {
      f32x2 a00 = {0, 0}, a01 = {0, 0}, a02 = {0, 0}, a03 = {0, 0};
      f32x2 a10 = {0, 0}, a11 = {0, 0}, a12 = {0, 0}, a13 = {0, 0};
#pragma unroll 4
      for (int u = 0; u < 64; ++u) {
        const f32x4 va = ld4(&Vs[u][b_r4]);   // V[b_r4..+3][u] via symmetry
        const f32x4 fb = ld4(Fb + u * 96 + b_c4);
        const f32x2 vl = va.lo, vh = va.hi, bl = fb.lo, bh = fb.hi;
        pk_lo(a00, vl, bl); pk_hi(a01, vl, bl);
        pk_lo(a02, vl, bh); pk_hi(a03, vl, bh);
        pk_lo(a10, vh, bl); pk_hi(a11, vh, bl);
        pk_lo(a12, vh, bh); pk_hi(a13, vh, bh);
      }
      st4(&Ws[b_r4 + 0][b_c4], a00.x, a01.x, a02.x, a03.x);
      st4(&Ws[b_r4 + 1][b_c4], a00.y, a01.y, a02.y, a03.y);
      st4(&Ws[b_r4 + 2][b_c4], a10.x, a11.x, a12.x, a13.x);
      st4(&Ws[b_r4 + 3][b_c4], a10.y, a11.y, a12.y, a13.y);
    } else if (tid < 448) {
      const int s = tid - 384;
      float acc = vv[s];
#pragma unroll
      for (int u4 = 0; u4 < 16; ++u4) {
        const f32x4 vr = ld4(&Vs[s][u4 * 4]);
        const f32x4 fr = ld4(cf + 256 + u4 * 4);
        acc += vr.x * fr.x + vr.y * fr.y + vr.z * fr.z + vr.w * fr.w;
      }
      hv[s] = acc;
    }

    // W#2: Ws visibility only (C lives in regs now)
    ASM_WAIT("lgkmcnt(0)");
    BAR();

    // ---- phase Qu/VsD/q:
    //  tid<192: Qu = Cu + Fu^T W | tid<448: Vs = Cxx + Fx^T W | wave7: q
    if (tid < 192) {
      f32x2 a00 = {c0.x, c1.x}, a01 = {c0.y, c1.y}, a02 = {c0.z, c1.z}, a03 = {c0.w, c1.w};
      f32x2 a10 = {c2.x, c3.x}, a11 = {c2.y, c3.y}, a12 = {c2.z, c3.z}, a13 = {c2.w, c3.w};
#pragma unroll 4
      for (int u = 0; u < 64; ++u) {
        const f32x4 fu = ld4(Fb + u * 96 + 64 + q_i0);
        const f32x4 w4 = ld4(&Ws[u][q_j0]);
        const f32x2 al = fu.lo, ah = fu.hi, bl = w4.lo, bh = w4.hi;
        pk_lo(a00, al, bl); pk_hi(a01, al, bl);
        pk_lo(a02, al, bh); pk_hi(a03, al, bh);
        pk_lo(a10, ah, bl); pk_hi(a11, ah, bl);
        pk_lo(a12, ah, bh); pk_hi(a13, ah, bh);
      }
      st4(&Qu[q_i0 + 0][q_j0], a00.x, a01.x, a02.x, a03.x);
      st4(&Qu[q_i0 + 1][q_j0], a00.y, a01.y, a02.y, a03.y);
      st4(&Qu[q_i0 + 2][q_j0], a10.x, a11.x, a12.x, a13.x);
      st4(&Qu[q_i0 + 3][q_j0], a10.y, a11.y, a12.y, a13.y);
    } else if (tid < 448) {
      f32x2 a00 = {c0.x, c1.x}, a01 = {c0.y, c1.y}, a02 = {c0.z, c1.z}, a03 = {c0.w, c1.w};
      f32x2 a10 = {c2.x, c3.x}, a11 = {c2.y, c3.y}, a12 = {c2.z, c3.z}, a13 = {c2.w, c3.w};
#pragma unroll 4
      for (int u = 0; u < 64; ++u) {
        const f32x4 fx = ld4(Fb + u * 96 + v_r);
        const f32x4 w4 = ld4(&Ws[u][v_c]);
        const f32x2 al = fx.lo, ah = fx.hi, bl = w4.lo, bh = w4.hi;
        pk_lo(a00, al, bl); pk_hi(a01, al, bl);
        pk_lo(a02, al, bh); pk_hi(a03, al, bh);
        pk_lo(a10, ah, bl); pk_hi(a11, ah, bl);
        pk_lo(a12, ah, bh); pk_hi(a13, ah, bh);
      }
      st4(&Vs[v_r + 0][v_c], a00.x, a01.x, a02.x, a03.x);
      st4(&Vs[v_r + 1][v_c], a00.y, a01.y, a02.y, a03.y);
      st4(&Vs[v_r + 2][v_c], a10.x, a11.x, a12.x, a13.x);
      st4(&Vs[v_r + 3][v_c], a10.y, a11.y, a12.y, a13.y);
    } else {
      const int j = tid - 448;                // 0..63 ; row j and (j+64 if j<32)
      float acc0 = cf[j];
      float acc1 = (j < 32) ? cf[64 + j] : 0.f;
#pragma unroll 4
      for (int s2 = 0; s2 < 64; ++s2) {
        const float hs = hv[s2];
        acc0 += Fb[s2 * 96 + j] * hs;
        if (j < 32) acc1 += Fb[s2 * 96 + 64 + j] * hs;
      }
      qv[j] = acc0;
      if (j < 32) qv[64 + j] = acc1;
    }

    ASM_WAIT("lgkmcnt(0)");
    BAR();

    // ---- phase D: register Cholesky (lanes 0-31, setprio-boosted)
    //              || deferred back-solve of step t+1 (tid 128..257)
    if (tid < 32) {
      __builtin_amdgcn_s_setprio(1);
      const int i = tid;
      float a[32];
#pragma unroll
      for (int k = 0; k < 32; ++k) a[k] = Qu[i][64 + k];
      float (*LTc)[33] = (float(*)[33])(smem + OFF_LT + cur * 1056);
      float* ivc = smem + OFF_INVD + cur * 32;
#pragma unroll
      for (int j = 0; j < 32; ++j) {
        const float d   = rdlane(a[j], j);
        const float rin = 1.0f / sqrtf(d);
        const float l   = a[j] * rin;         // L[i][j] (valid i>=j)
        LTc[j][i] = l;
        if (i == 0) ivc[j] = rin;
#pragma unroll
        for (int k = j + 1; k < 32; ++k) {
          const float lkj = rdlane(l, k);
          a[k] = fmaf(-l, lkj, a[k]);
        }
      }
      __builtin_amdgcn_s_setprio(0);
    } else if (tid >= 128 && tid < 258) {
      if (t != T_ - 1) backsolve2(cur ^ 1, (size_t)(t + 1) * B_ + b);
    }

    ASM_WAIT("lgkmcnt(0)");
    BAR();

    // ---- phase E: forward solve Y = L^{-1}[Qux|qu] (tid<65, rank-1 form)
    if (tid < 65) {
      const float (*LTc)[33] = (const float(*)[33])(smem + OFF_LT + cur * 1056);
      const float* ivc = smem + OFF_INVD + cur * 32;
      float r[32];
#pragma unroll
      for (int i2 = 0; i2 < 32; ++i2)
        r[i2] = (tid < 64) ? Qu[i2][tid] : qv[64 + i2];
#pragma unroll
      for (int i2 = 0; i2 < 32; ++i2) {
        const float yi = r[i2] * ivc[i2];
        r[i2] = yi;
#pragma unroll
        for (int k = i2 + 1; k < 32; ++k) r[k] -= LTc[i2][k] * yi;
      }
      float (*Sc)[68] = (float(*)[68])(smem + OFF_SS + cur * 2176);
#pragma unroll
      for (int i2 = 0; i2 < 32; ++i2) Sc[i2][tid] = r[i2];
    }

    ASM_WAIT("lgkmcnt(0)");
    BAR();

    // ---- phase F: V -= Y^T Y (tid>=256, packed 4x4); vn = qx - Y^T y (tid<64)
    {
      const float (*Sc)[68] = (const float(*)[68])(smem + OFF_SS + cur * 2176);
      if (tid >= 256) {
        f32x2 p00 = {0, 0}, p01 = {0, 0}, p02 = {0, 0}, p03 = {0, 0};
        f32x2 p10 = {0, 0}, p11 = {0, 0}, p12 = {0, 0}, p13 = {0, 0};
#pragma unroll 4
        for (int m = 0; m < 32; ++m) {
          const f32x4 ya = ld4(&Sc[m][f_i]);
          const f32x4 yb = ld4(&Sc[m][f_j]);
          const f32x2 al = ya.lo, ah = ya.hi, bl = yb.lo, bh = yb.hi;
          pk_lo(p00, al, bl); pk_hi(p01, al, bl);
          pk_lo(p02, al, bh); pk_hi(p03, al, bh);
          pk_lo(p10, ah, bl); pk_hi(p11, ah, bl);
          pk_lo(p12, ah, bh); pk_hi(p13, ah, bh);
        }
        f32x4 v0 = ld4(&Vs[f_i + 0][f_j]);
        f32x4 v1 = ld4(&Vs[f_i + 1][f_j]);
        f32x4 v2 = ld4(&Vs[f_i + 2][f_j]);
        f32x4 v3 = ld4(&Vs[f_i + 3][f_j]);
        st4(&Vs[f_i + 0][f_j], v0.x - p00.x, v0.y - p01.x, v0.z - p02.x, v0.w - p03.x);
        st4(&Vs[f_i + 1][f_j], v1.x - p00.y, v1.y - p01.y, v1.z - p02.y, v1.w - p03.y);
        st4(&Vs[f_i + 2][f_j], v2.x - p10.x, v2.y - p11.x, v2.z - p12.x, v2.w - p13.x);
        st4(&Vs[f_i + 3][f_j], v3.x - p10.y, v3.y - p11.y, v3.z - p12.y, v3.w - p13.y);
      } else if (tid < 64) {
        float acc = qv[tid];
#pragma unroll 4
        for (int m = 0; m < 32; ++m) acc -= Sc[m][tid] * Sc[m][64];
        vv[tid] = acc;
      }
    }
    // no trailing barrier: next W#1 (wait+bar) covers all hazards
    cur ^= 1;
  }

  // ---- epilogue: back-solve for t=0 (its Y/LT/invd live in buffer 1)
  ASM_WAIT("vmcnt(0) lgkmcnt(0)");
  BAR();
  if (tid >= 128 && tid < 258) backsolve2(1, (size_t)b);
  ASM_WAIT("vmcnt(0) lgkmcnt(0)");   // S stores must land before fwd re-reads
  BAR();

  // ================= forward rollout =================
  float* tf = smem + OFF_QV;                   // tau: [0:64]=x, [64:96]=u
  if (tid < 64) tf[tid] = x0g[(size_t)b * 64 + tid];

  auto stage_fwd = [&](int ts, int nb) {       // 6 instrs/wave: S(2) F(3) f(1)
    const size_t tbs = (size_t)ts * B_ + b;
    const float* Sb = Sws + tbs * 2080;
    float* sdst = smem + OFF_WS + nb * 2304;
#pragma unroll
    for (int r = 0; r < 2; ++r) {
      int q = wid * 2 + r; if (q > 8) q = 8;   // 9 chunks, dup tail (benign)
      const int off = q * 256 + lane * 4;
      g2l16(Sb + (off < 2080 ? off : 2076), sdst + q * 256);
    }
    const float* Fbase = Fg + tbs * (NS_ * NSC_);
    float* fdst = smem + OFF_FB + nb * 6144;
#pragma unroll
    for (int r = 0; r < 3; ++r) {
      const int q = wid * 3 + r;
      g2l16(Fbase + q * 256 + lane * 4, fdst + q * 256);
    }
    const int o = lane * 4;
    g2l16(fvg + tbs * 64 + (o < 64 ? o : 60), smem + OFF_CF + nb * 512);
  };

  stage_fwd(0, 0);
  cur = 0;
  const int s4 = tid >> 2, l4 = tid & 3;       // x-row ownership (tid<256)
  for (int t = 0; t < T_; ++t) {
    const size_t tb = (size_t)t * B_ + b;
    stage_fwd((t < T_ - 1) ? t + 1 : T_ - 1, cur ^ 1);
    ASM_WAIT("vmcnt(6) lgkmcnt(0)");
    BAR();

    const float* Fbc = smem + OFF_FB + cur * 6144;
    float ax = 0.f;

    // phase 1: emit x | ax = Fx x (tid<256, 4/row) | u = -(S tau) (tid>=256)
    if (tid < 64) outg[tb * 96 + tid] = tf[tid];
    if (tid < 256) {
      const float* Fr = Fbc + s4 * 96 + l4 * 16;
#pragma unroll
      for (int q = 0; q < 4; ++q) {
        const f32x4 fq = ld4(Fr + q * 4);
        const f32x4 xq = ld4(&tf[l4 * 16 + q * 4]);
        ax += fq.x * xq.x + fq.y * xq.y + fq.z * xq.z + fq.w * xq.w;
      }
    } else {
      const int m = (tid - 256) >> 3, l8 = tid & 7;
      const float* Sr = smem + OFF_WS + cur * 2304 + m * 65;
      float p = (l8 == 0) ? Sr[64] : 0.f;
      const int i0 = l8 * 8;
#pragma unroll
      for (int ii = 0; ii < 8; ++ii) p += Sr[i0 + ii] * tf[i0 + ii];
      p += __shfl_xor(p, 1); p += __shfl_xor(p, 2); p += __shfl_xor(p, 4);
      if (l8 == 0) tf[64 + m] = -p;
    }
    ASM_WAIT("lgkmcnt(0)");
    BAR();

    // phase 2: x_next = ax + Fu u + f -> tf[0:64] | emit u (tid 256..287)
    if (tid < 256) {
      const float* Fu = Fbc + s4 * 96 + 64 + l4 * 8;
      const f32x4 g0 = ld4(Fu);
      const f32x4 g1 = ld4(Fu + 4);
      const f32x4 u0 = ld4(&tf[64 + l4 * 8]);
      const f32x4 u1 = ld4(&tf[64 + l4 * 8 + 4]);
      float p = ax + g0.x * u0.x + g0.y * u0.y + g0.z * u0.z + g0.w * u0.w
                   + g1.x * u1.x + g1.y * u1.y + g1.z * u1.z + g1.w * u1.w;
      p += __shfl_xor(p, 1); p += __shfl_xor(p, 2);
      if (l4 == 0) tf[s4] = p + *(smem + OFF_CF + cur * 512 + s4);
    } else if (tid < 288) {
      const int m = tid - 256;
      outg[tb * 96 + 64 + m] = tf[64 + m];
    }
    ASM_WAIT("lgkmcnt(0)");
    BAR();
    cur ^= 1;
  }
}

extern "C" void kernel_launch(void* const* d_in, const int* in_sizes, int n_in,
                              void* d_out, int out_size, void* d_ws, size_t ws_size,
                              hipStream_t stream) {
  const float* C  = (const float*)d_in[0];
  const float* c  = (const float*)d_in[1];
  const float* F  = (const float*)d_in[2];
  const float* f  = (const float*)d_in[3];
  const float* x0 = (const float*)d_in[4];
  float* out = (float*)d_out;
  float* S   = (float*)d_ws;   // needs T*B*32*65*4 = 68.2 MB

  lqr_all<<<dim3(B_), dim3(512), 0, stream>>>(C, c, F, f, x0, out, S);
}